// Round 16
// baseline (261.466 us; speedup 1.0000x reference)
//
#include <hip/hip_runtime.h>
#include <hip/hip_bf16.h>
#include <hip/hip_cooperative_groups.h>

namespace cg = cooperative_groups;

// Problem constants
#define B 4
#define N 2048
#define D 512
#define H 8
#define DH 64
#define ROWS (B * N)        // 8192
#define AWIN 48             // attn band half-width; tail < 5e-5
#define LPAD 64             // left col pad in Vt
#define RPAD 128            // right col pad in Vt
#define SEG (LPAD + N + RPAD)   // 2240 cols per batch in Vt
#define LDV (B * SEG)           // 8960 = Vt row length
#define GBK 64
#define GK  512

using bf16x8 = __attribute__((ext_vector_type(8))) short;
using f32x4  = __attribute__((ext_vector_type(4))) float;
using f32x16 = __attribute__((ext_vector_type(16))) float;

static __device__ __forceinline__ unsigned short f2bf(float f) {
    unsigned u = __builtin_bit_cast(unsigned, f);
    u += 0x7fffu + ((u >> 16) & 1u);        // round-to-nearest-even
    return (unsigned short)(u >> 16);
}
static __device__ __forceinline__ unsigned pack2(float a, float b) {
    return (unsigned)f2bf(a) | ((unsigned)f2bf(b) << 16);
}

// ---------------- phase 0: prep job (2240 jobs) -------------------------------
static __device__ void prep_job(int bx, const float* __restrict__ x,
                                const float* __restrict__ Ws,
                                const float* __restrict__ bs,
                                const float* __restrict__ Wv,
                                const float* __restrict__ Wo,
                                unsigned short* __restrict__ xbf,
                                float* __restrict__ l2rbuf,
                                unsigned short* __restrict__ WvT,
                                unsigned short* __restrict__ WoT,
                                unsigned short* __restrict__ Vt,
                                char* smem) {
    if (bx < 2048) {
        // ---- x convert + f32 sigma (precision-critical: feeds exp chain) ----
        const int wid = threadIdx.x >> 6, lane = threadIdx.x & 63;
        const int row = bx * 4 + wid;
        const float* xr = x + (size_t)row * D + lane * 8;
        const float4 a = *reinterpret_cast<const float4*>(xr);
        const float4 c = *reinterpret_cast<const float4*>(xr + 4);
        float v[8] = {a.x, a.y, a.z, a.w, c.x, c.y, c.z, c.w};

        uint4 o;
        o.x = pack2(v[0], v[1]); o.y = pack2(v[2], v[3]);
        o.z = pack2(v[4], v[5]); o.w = pack2(v[6], v[7]);
        *reinterpret_cast<uint4*>(xbf + (size_t)row * D + lane * 8) = o;

        const float4* Ws4 = reinterpret_cast<const float4*>(Ws);   // (D, 8)
        f32x4 alo = (f32x4)0.0f, ahi = (f32x4)0.0f;
#pragma unroll
        for (int j = 0; j < 8; j++) {
            const int e = lane * 8 + j;
            const float4 wl = Ws4[e * 2], wh = Ws4[e * 2 + 1];
            alo[0] += v[j] * wl.x; alo[1] += v[j] * wl.y; alo[2] += v[j] * wl.z; alo[3] += v[j] * wl.w;
            ahi[0] += v[j] * wh.x; ahi[1] += v[j] * wh.y; ahi[2] += v[j] * wh.z; ahi[3] += v[j] * wh.w;
        }
#pragma unroll
        for (int off = 1; off < 64; off <<= 1) {
#pragma unroll
            for (int c2 = 0; c2 < 4; c2++) {
                alo[c2] += __shfl_xor(alo[c2], off, 64);
                ahi[c2] += __shfl_xor(ahi[c2], off, 64);
            }
        }
        if (lane < 8) {
            const int h = lane;
            const float acc = (h < 4) ? alo[h] : ahi[h - 4];
            const float z = acc + bs[h];
            const float sig = 1.0f / (1.0f + expf(-z));
            const float s = expf(sig) + 1.0f;
            l2rbuf[(size_t)row * H + h] = -1.4426950408889634f / s;
        }
        return;
    }

    if (bx < 2176) {
        // ---- W transpose+convert (uses smem tile, 64x65 f32) ----
        float (*tile)[65] = (float (*)[65])smem;
        const int idx = bx - 2048;
        const bool second = idx >= 64;
        const int id2 = idx & 63;
        const float* src = second ? Wo : Wv;
        unsigned short* dst = second ? WoT : WvT;
        const int n0 = (id2 & 7) * 64, k0 = (id2 >> 3) * 64;
        const int tr = threadIdx.x >> 4, tc = threadIdx.x & 15;
#pragma unroll
        for (int it = 0; it < 4; it++) {
            const int r = it * 16 + tr;
            const float4 v = *reinterpret_cast<const float4*>(&src[(size_t)(k0 + r) * 512 + n0 + tc * 4]);
            tile[r][tc * 4 + 0] = v.x; tile[r][tc * 4 + 1] = v.y;
            tile[r][tc * 4 + 2] = v.z; tile[r][tc * 4 + 3] = v.w;
        }
        __syncthreads();
#pragma unroll
        for (int it = 0; it < 4; it++) {
            const int r = it * 16 + tr;
            ushort4 o;
            o.x = f2bf(tile[tc * 4 + 0][r]); o.y = f2bf(tile[tc * 4 + 1][r]);
            o.z = f2bf(tile[tc * 4 + 2][r]); o.w = f2bf(tile[tc * 4 + 3][r]);
            *reinterpret_cast<ushort4*>(&dst[(size_t)(n0 + r) * 512 + k0 + tc * 4]) = o;
        }
        __syncthreads();   // guard tile reuse across sequential jobs
        return;
    }

    // ---- zero pad cols of Vt ----
    {
        const int idx = bx - 2176;   // 0..63
        for (int t = idx * 256 + threadIdx.x; t < 512 * 4 * 24; t += 64 * 256) {
            const int c = t % 24;
            const int bb = (t / 24) & 3;
            const int row = t / 96;
            const int col = (c < 8) ? bb * SEG + c * 8 : bb * SEG + LPAD + N + (c - 8) * 8;
            *reinterpret_cast<uint4*>(Vt + (size_t)row * LDV + col) = uint4{0, 0, 0, 0};
        }
    }
}

// ---------------- GEMM body: 64x64 tile, GBK=64, dbuf, XOR-swizzled LDS -------
// MODE 0: f32 out + bias. MODE 2: bf16 out into Vt with col remap.
template <int MODE>
static __device__ void gemm_body(int bm, int bn,
                                 const unsigned short* __restrict__ A,
                                 const unsigned short* __restrict__ Bt,
                                 const float* __restrict__ bias,
                                 void* __restrict__ Cout, int ldc,
                                 char* smem) {
    auto As = (unsigned short (*)[64][GBK])(smem);            // [2][64][64] 16 KB
    auto Bs = (unsigned short (*)[64][GBK])(smem + 16384);    // [2][64][64] 16 KB
    const int tid = threadIdx.x;
    const int lane = tid & 63, wid = tid >> 6;
    const int wr = wid >> 1, wc = wid & 1;      // 2x2 waves: 32x32 each
    const int fr = lane & 15, kg = lane >> 4;

    f32x4 acc[2][2] = {};

    const unsigned short* Ab = A + (size_t)bm * 64 * GK;
    const unsigned short* Bb = Bt + (size_t)bn * 64 * GK;
    const int r32 = tid >> 3, ch = tid & 7;     // 32 rows/pass, chunk 0..7

    auto stage = [&](int buf, int k0) {
#pragma unroll
        for (int it = 0; it < 2; it++) {
            const int row = it * 32 + r32;
            const int gch = ch ^ (row & 7);     // pre-swizzled global source
            const unsigned short* g = Ab + (size_t)row * GK + k0 + gch * 8;
            __builtin_amdgcn_global_load_lds(
                (const __attribute__((address_space(1))) void*)g,
                (__attribute__((address_space(3))) void*)&As[buf][row][ch * 8], 16, 0, 0);
        }
#pragma unroll
        for (int it = 0; it < 2; it++) {
            const int row = it * 32 + r32;
            const int gch = ch ^ (row & 7);
            const unsigned short* g = Bb + (size_t)row * GK + k0 + gch * 8;
            __builtin_amdgcn_global_load_lds(
                (const __attribute__((address_space(1))) void*)g,
                (__attribute__((address_space(3))) void*)&Bs[buf][row][ch * 8], 16, 0, 0);
        }
    };

    stage(0, 0);
    __syncthreads();
    int cur = 0;
#pragma unroll
    for (int kt = 0; kt < GK / GBK; kt++) {
        if (kt + 1 < GK / GBK) stage(cur ^ 1, (kt + 1) * GBK);
#pragma unroll
        for (int ks = 0; ks < 2; ks++) {
            bf16x8 af[2], bfr[2];
#pragma unroll
            for (int m = 0; m < 2; m++) {
                const int arow = wr * 32 + m * 16 + fr;
                const int rch = (ks * 4 + kg) ^ (arow & 7);   // swizzled read col
                af[m] = *reinterpret_cast<const bf16x8*>(&As[cur][arow][rch * 8]);
            }
#pragma unroll
            for (int n = 0; n < 2; n++) {
                const int brow = wc * 32 + n * 16 + fr;
                const int rch = (ks * 4 + kg) ^ (brow & 7);
                bfr[n] = *reinterpret_cast<const bf16x8*>(&Bs[cur][brow][rch * 8]);
            }
#pragma unroll
            for (int m = 0; m < 2; m++)
#pragma unroll
                for (int n = 0; n < 2; n++)
                    acc[m][n] = __builtin_amdgcn_mfma_f32_16x16x32_bf16(af[m], bfr[n], acc[m][n], 0, 0, 0);
        }
        __syncthreads();
        cur ^= 1;
    }

#pragma unroll
    for (int n = 0; n < 2; n++) {
        const int col = bn * 64 + wc * 32 + n * 16 + fr;
        const float bv = (MODE == 0 && bias) ? bias[col] : 0.0f;
        const int cp = (MODE == 2) ? ((col >> 11) * SEG + LPAD + (col & 2047)) : col;
#pragma unroll
        for (int m = 0; m < 2; m++) {
            const int row0 = bm * 64 + wr * 32 + m * 16 + kg * 4;
#pragma unroll
            for (int j = 0; j < 4; j++) {
                const int row = row0 + j;
                if (MODE == 0)
                    ((float*)Cout)[(size_t)row * ldc + col] = acc[m][n][j] + bv;
                else
                    ((unsigned short*)Cout)[(size_t)row * ldc + cp] = f2bf(acc[m][n][j]);
            }
        }
    }
}

// ---------------- attn body: 32x32x16 MFMA, d-split ---------------------------
static __device__ void attn_body(int bid, const unsigned short* __restrict__ Vt,
                                 const float* __restrict__ l2rbuf,
                                 unsigned short* __restrict__ O) {
    const int wid = threadIdx.x >> 6;
    const int lane = threadIdx.x & 63;
    const int il = lane & 31, hi = lane >> 5;
    const int sbid = (bid & 7) * 128 + (bid >> 3);   // bijective XCD swizzle
    const int gi = sbid * 4 + wid;             // over (b,h,iblk,dhalf), 4096
    const int dhalf = gi & 1;
    const int iblk = (gi >> 1) & 63;           // N/32 = 64
    const int bh = gi >> 7;
    const int h = bh & 7;
    const int b = bh >> 3;
    const int i0 = iblk * 32;

    const int i = i0 + il;                     // this lane's query row (C col)
    const float l2rf = l2rbuf[((size_t)(b * N + i)) * H + h];

    const unsigned short* Va = Vt + (size_t)(h * DH + dhalf * 32 + il) * LDV
                              + (size_t)b * SEG + (LPAD - AWIN) + i0 + hi * 8;

    f32x16 acc = (f32x16)0.0f;
    __builtin_amdgcn_s_setprio(1);
#pragma unroll
    for (int ks = 0; ks < 8; ks++) {
        const float jb = (float)(ks * 16 + hi * 8 - AWIN - il);
        float wv[8];
#pragma unroll
        for (int e = 0; e < 8; e++)
            wv[e] = __builtin_amdgcn_exp2f(l2rf * __builtin_fabsf(jb + (float)e));
        uint4 uw;
        uw.x = pack2(wv[0], wv[1]); uw.y = pack2(wv[2], wv[3]);
        uw.z = pack2(wv[4], wv[5]); uw.w = pack2(wv[6], wv[7]);
        const bf16x8 pB = __builtin_bit_cast(bf16x8, uw);
        const bf16x8 a0 = *reinterpret_cast<const bf16x8*>(Va + (size_t)ks * 16);
        acc = __builtin_amdgcn_mfma_f32_32x32x16_bf16(a0, pB, acc, 0, 0, 0);
    }
    __builtin_amdgcn_s_setprio(0);

    const float rr = __builtin_amdgcn_exp2f(l2rf);
    const float inv1mr = 1.0f / (1.0f - rr);
    const float rl = __builtin_amdgcn_exp2f(l2rf * (float)(i + 1));
    const float rg = __builtin_amdgcn_exp2f(l2rf * (float)(N - i));
    const float invz = 1.0f / (1.0f + (2.0f * rr - rl - rg) * inv1mr);

    unsigned short* orow = O + ((size_t)(b * N + i)) * D + h * DH + dhalf * 32 + 4 * hi;
#pragma unroll
    for (int q = 0; q < 4; q++) {
        uint2 o0;
        o0.x = pack2(acc[4 * q + 0] * invz, acc[4 * q + 1] * invz);
        o0.y = pack2(acc[4 * q + 2] * invz, acc[4 * q + 3] * invz);
        *reinterpret_cast<uint2*>(orow + 8 * q) = o0;
    }
}

// ---------------- cooperative mega-kernel: 512 blocks, grid-stride phases -----
__global__ void __launch_bounds__(256, 2)
mega(const float* x, const float* Ws, const float* bs,
     const float* Wv, const float* Wo, const float* bo,
     float* out, unsigned short* Vt, unsigned short* xbf,
     unsigned short* WvT, unsigned short* WoT, float* l2r) {
    __shared__ __align__(16) char smem[32768];
    cg::grid_group grid = cg::this_grid();

    for (int job = blockIdx.x; job < 2240; job += 512)
        prep_job(job, x, Ws, bs, Wv, Wo, xbf, l2r, WvT, WoT, Vt, smem);
    grid.sync();

    for (int t = blockIdx.x; t < 1024; t += 512)
        gemm_body<2>(t >> 7, t & 127, WvT, xbf, nullptr, Vt, LDV, smem);
    grid.sync();

    for (int t = blockIdx.x; t < 1024; t += 512)
        attn_body(t, Vt, l2r, xbf);          // attnOut aliases xbf (GEMM1 done)
    grid.sync();

    for (int t = blockIdx.x; t < 1024; t += 512) {
        const int xcd = t & 7, idx = t >> 3;
        gemm_body<0>(xcd * 16 + (idx >> 3), idx & 7, xbf, WoT, bo, out, D, smem);
    }
}

// ---------------- fallback wrappers (exact R14 path) --------------------------
__global__ __launch_bounds__(256) void prep_kernel(const float* x, const float* Ws,
                                                   const float* bs, const float* Wv,
                                                   const float* Wo, unsigned short* xbf,
                                                   float* l2r, unsigned short* WvT,
                                                   unsigned short* WoT, unsigned short* Vt) {
    __shared__ __align__(16) char smem[16640];
    prep_job(blockIdx.x, x, Ws, bs, Wv, Wo, xbf, l2r, WvT, WoT, Vt, smem);
}
__global__ __launch_bounds__(256) void gemm1_kernel(const unsigned short* A,
                                                    const unsigned short* Bt,
                                                    unsigned short* Vt) {
    __shared__ __align__(16) char smem[32768];
    gemm_body<2>(blockIdx.y, blockIdx.x, A, Bt, nullptr, Vt, LDV, smem);
}
__global__ __launch_bounds__(256) void attn_kernel(const unsigned short* Vt,
                                                   const float* l2r,
                                                   unsigned short* O) {
    attn_body(blockIdx.x, Vt, l2r, O);
}
__global__ __launch_bounds__(256) void gemm2_kernel(const unsigned short* A,
                                                    const unsigned short* Bt,
                                                    const float* bias, float* out) {
    __shared__ __align__(16) char smem[32768];
    const int xcd = blockIdx.x & 7, idx = blockIdx.x >> 3;
    gemm_body<0>(xcd * 16 + (idx >> 3), idx & 7, A, Bt, bias, out, D, smem);
}

extern "C" void kernel_launch(void* const* d_in, const int* in_sizes, int n_in,
                              void* d_out, int out_size, void* d_ws, size_t ws_size,
                              hipStream_t stream) {
    const float* x      = (const float*)d_in[0];   // (B,N,D)
    const float* W_v    = (const float*)d_in[1];   // (D, 512)
    const float* W_sig  = (const float*)d_in[2];   // (D, H)
    const float* b_sig  = (const float*)d_in[3];   // (H,)
    const float* W_out  = (const float*)d_in[4];   // (512, D)
    const float* b_out  = (const float*)d_in[5];   // (D,)
    float* out = (float*)d_out;

    char* ws = (char*)d_ws;
    unsigned short* Vt   = (unsigned short*)ws;                                // 8.75 MB
    unsigned short* xbf  = (unsigned short*)(ws + (size_t)9  * 1024 * 1024);   // 8 MB (reused as attnOut)
    unsigned short* WvT  = (unsigned short*)(ws + (size_t)17 * 1024 * 1024);   // 512 KB
    unsigned short* WoT  = (unsigned short*)(ws + (size_t)17 * 1024 * 1024 + 524288);
    float*          l2r  = (float*)(ws + (size_t)18 * 1024 * 1024);            // 256 KB

    // Deterministic coop-viability check (pure host queries, capture-safe)
    int coopAttr = 0, dev = 0, maxBlk = 0;
    bool coop = false;
    if (hipGetDevice(&dev) == hipSuccess &&
        hipDeviceGetAttribute(&coopAttr, hipDeviceAttributeCooperativeLaunch, dev) == hipSuccess &&
        coopAttr != 0 &&
        hipOccupancyMaxActiveBlocksPerMultiprocessor(&maxBlk, (const void*)mega, 256, 0) == hipSuccess &&
        maxBlk >= 2) {
        coop = true;   // 512 blocks need 2/CU on 256 CUs
    }

    if (coop) {
        void* args[12] = {
            (void*)&x, (void*)&W_sig, (void*)&b_sig, (void*)&W_v, (void*)&W_out,
            (void*)&b_out, (void*)&out, (void*)&Vt, (void*)&xbf, (void*)&WvT,
            (void*)&WoT, (void*)&l2r
        };
        hipLaunchCooperativeKernel((const void*)mega, dim3(512), dim3(256),
                                   args, 0, stream);
    } else {
        prep_kernel<<<2240, 256, 0, stream>>>(x, W_sig, b_sig, W_v, W_out,
                                              xbf, l2r, WvT, WoT, Vt);
        {
            dim3 grid(128, 8);
            gemm1_kernel<<<grid, 256, 0, stream>>>(WvT, xbf, Vt);
        }
        attn_kernel<<<1024, 256, 0, stream>>>(Vt, l2r, xbf);
        gemm2_kernel<<<1024, 256, 0, stream>>>(xbf, WoT, b_out, out);
    }
}

// Round 17
// 57.228 us; speedup vs baseline: 4.5688x; 4.5688x over previous
//
#include <hip/hip_runtime.h>
#include <hip/hip_bf16.h>

// Problem constants
#define B 4
#define N 2048
#define D 512
#define H 8
#define DH 64
#define ROWS (B * N)        // 8192
#define AWIN 48             // attn band half-width; tail < 5e-5
#define LPAD 64             // left col pad in Vt
#define RPAD 128            // right col pad in Vt
#define SEG (LPAD + N + RPAD)   // 2240 cols per batch in Vt
#define LDV (B * SEG)           // 8960 = Vt row length

using bf16x8 = __attribute__((ext_vector_type(8))) short;
using f32x4  = __attribute__((ext_vector_type(4))) float;
using f32x16 = __attribute__((ext_vector_type(16))) float;

static __device__ __forceinline__ unsigned short f2bf(float f) {
    unsigned u = __builtin_bit_cast(unsigned, f);
    u += 0x7fffu + ((u >> 16) & 1u);        // round-to-nearest-even
    return (unsigned short)(u >> 16);
}
static __device__ __forceinline__ unsigned pack2(float a, float b) {
    return (unsigned)f2bf(a) | ((unsigned)f2bf(b) << 16);
}

// ------------- fused prep: x->bf16 + f32 sigma (blocks 0..2047),
//               WvT (2048..2111), WoT (2112..2175), Vt pad zero (2176..2239) ---
__global__ __launch_bounds__(256) void prep_fused(const float* __restrict__ x,
                                                  const float* __restrict__ Ws,
                                                  const float* __restrict__ bs,
                                                  const float* __restrict__ Wv,
                                                  const float* __restrict__ Wo,
                                                  unsigned short* __restrict__ xbf,
                                                  float* __restrict__ l2rbuf,
                                                  unsigned short* __restrict__ WvT,
                                                  unsigned short* __restrict__ WoT,
                                                  unsigned short* __restrict__ Vt) {
    __shared__ float tile[64][65];
    const int bx = blockIdx.x;

    if (bx < 2048) {
        // ---- x convert + f32 sigma (precision-critical: feeds exp chain) ----
        const int wid = threadIdx.x >> 6, lane = threadIdx.x & 63;
        const int row = bx * 4 + wid;
        const float* xr = x + (size_t)row * D + lane * 8;
        const float4 a = *reinterpret_cast<const float4*>(xr);
        const float4 c = *reinterpret_cast<const float4*>(xr + 4);
        float v[8] = {a.x, a.y, a.z, a.w, c.x, c.y, c.z, c.w};

        uint4 o;
        o.x = pack2(v[0], v[1]); o.y = pack2(v[2], v[3]);
        o.z = pack2(v[4], v[5]); o.w = pack2(v[6], v[7]);
        *reinterpret_cast<uint4*>(xbf + (size_t)row * D + lane * 8) = o;

        const float4* Ws4 = reinterpret_cast<const float4*>(Ws);   // (D, 8)
        f32x4 alo = (f32x4)0.0f, ahi = (f32x4)0.0f;
#pragma unroll
        for (int j = 0; j < 8; j++) {
            const int e = lane * 8 + j;
            const float4 wl = Ws4[e * 2], wh = Ws4[e * 2 + 1];
            alo[0] += v[j] * wl.x; alo[1] += v[j] * wl.y; alo[2] += v[j] * wl.z; alo[3] += v[j] * wl.w;
            ahi[0] += v[j] * wh.x; ahi[1] += v[j] * wh.y; ahi[2] += v[j] * wh.z; ahi[3] += v[j] * wh.w;
        }
#pragma unroll
        for (int off = 1; off < 64; off <<= 1) {
#pragma unroll
            for (int c2 = 0; c2 < 4; c2++) {
                alo[c2] += __shfl_xor(alo[c2], off, 64);
                ahi[c2] += __shfl_xor(ahi[c2], off, 64);
            }
        }
        if (lane < 8) {
            const int h = lane;
            const float acc = (h < 4) ? alo[h] : ahi[h - 4];
            const float z = acc + bs[h];
            const float sig = 1.0f / (1.0f + expf(-z));
            const float s = expf(sig) + 1.0f;
            l2rbuf[(size_t)row * H + h] = -1.4426950408889634f / s;
        }
        return;
    }

    if (bx < 2176) {
        // ---- W transpose+convert ----
        const int idx = bx - 2048;
        const bool second = idx >= 64;
        const int id2 = idx & 63;
        const float* src = second ? Wo : Wv;
        unsigned short* dst = second ? WoT : WvT;
        const int n0 = (id2 & 7) * 64, k0 = (id2 >> 3) * 64;
        const int tr = threadIdx.x >> 4, tc = threadIdx.x & 15;
#pragma unroll
        for (int it = 0; it < 4; it++) {
            const int r = it * 16 + tr;
            const float4 v = *reinterpret_cast<const float4*>(&src[(size_t)(k0 + r) * 512 + n0 + tc * 4]);
            tile[r][tc * 4 + 0] = v.x; tile[r][tc * 4 + 1] = v.y;
            tile[r][tc * 4 + 2] = v.z; tile[r][tc * 4 + 3] = v.w;
        }
        __syncthreads();
#pragma unroll
        for (int it = 0; it < 4; it++) {
            const int r = it * 16 + tr;
            ushort4 o;
            o.x = f2bf(tile[tc * 4 + 0][r]); o.y = f2bf(tile[tc * 4 + 1][r]);
            o.z = f2bf(tile[tc * 4 + 2][r]); o.w = f2bf(tile[tc * 4 + 3][r]);
            *reinterpret_cast<ushort4*>(&dst[(size_t)(n0 + r) * 512 + k0 + tc * 4]) = o;
        }
        return;
    }

    // ---- zero pad cols of Vt ----
    {
        const int idx = bx - 2176;   // 0..63
        for (int t = idx * 256 + threadIdx.x; t < 512 * 4 * 24; t += 64 * 256) {
            const int c = t % 24;
            const int bb = (t / 24) & 3;
            const int row = t / 96;
            const int col = (c < 8) ? bb * SEG + c * 8 : bb * SEG + LPAD + N + (c - 8) * 8;
            *reinterpret_cast<uint4*>(Vt + (size_t)row * LDV + col) = uint4{0, 0, 0, 0};
        }
    }
}

// ---------------- bf16 MFMA GEMM, 64x64 tile, GBK=64, double-buffered ---------
// LDS XOR-swizzle (rule #21): linear LDS dest, pre-swizzled GLOBAL source chunk
// (ch ^ (row&7)), and the same XOR applied on the ds_read col. Breaks the
// 128-byte-row 16-way bank conflict on fragment reads.
// MODE 0: f32 out + bias, 1D grid 1024 with bijective XCD swizzle.
// MODE 2: bf16 out into Vt with col remap, 2D grid (bn=128, bm=8).
#define GBK 64
#define GK  512

template <int MODE>
__global__ __launch_bounds__(256) void gemm_bf16(const unsigned short* __restrict__ A,
                                                 const unsigned short* __restrict__ Bt,
                                                 const float* __restrict__ bias,
                                                 void* __restrict__ Cout,
                                                 int ldc) {
    __shared__ unsigned short As[2][64][GBK];   // 8 KB x2
    __shared__ unsigned short Bs[2][64][GBK];   // 8 KB x2 (32 KB total)
    const int tid = threadIdx.x;
    const int lane = tid & 63, wid = tid >> 6;
    const int wr = wid >> 1, wc = wid & 1;      // 2x2 waves: 32x32 each
    int bm, bn;
    if (MODE == 0) {
        const int xcd = blockIdx.x & 7, idx = blockIdx.x >> 3;
        bm = xcd * 16 + (idx >> 3);
        bn = idx & 7;
    } else {
        bn = blockIdx.x; bm = blockIdx.y;
    }
    const int fr = lane & 15, kg = lane >> 4;

    f32x4 acc[2][2] = {};

    const unsigned short* Ab = A + (size_t)bm * 64 * GK;
    const unsigned short* Bb = Bt + (size_t)bn * 64 * GK;
    const int r32 = tid >> 3, ch = tid & 7;     // 32 rows/pass, chunk 0..7

    auto stage = [&](int buf, int k0) {
#pragma unroll
        for (int it = 0; it < 2; it++) {
            const int row = it * 32 + r32;
            const int gch = ch ^ (row & 7);     // pre-swizzled global source
            const unsigned short* g = Ab + (size_t)row * GK + k0 + gch * 8;
            __builtin_amdgcn_global_load_lds(
                (const __attribute__((address_space(1))) void*)g,
                (__attribute__((address_space(3))) void*)&As[buf][row][ch * 8], 16, 0, 0);
        }
#pragma unroll
        for (int it = 0; it < 2; it++) {
            const int row = it * 32 + r32;
            const int gch = ch ^ (row & 7);
            const unsigned short* g = Bb + (size_t)row * GK + k0 + gch * 8;
            __builtin_amdgcn_global_load_lds(
                (const __attribute__((address_space(1))) void*)g,
                (__attribute__((address_space(3))) void*)&Bs[buf][row][ch * 8], 16, 0, 0);
        }
    };

    stage(0, 0);
    __syncthreads();
    int cur = 0;
#pragma unroll
    for (int kt = 0; kt < GK / GBK; kt++) {
        if (kt + 1 < GK / GBK) stage(cur ^ 1, (kt + 1) * GBK);
#pragma unroll
        for (int ks = 0; ks < 2; ks++) {
            bf16x8 af[2], bfr[2];
#pragma unroll
            for (int m = 0; m < 2; m++) {
                const int arow = wr * 32 + m * 16 + fr;
                const int rch = (ks * 4 + kg) ^ (arow & 7);   // swizzled read col
                af[m] = *reinterpret_cast<const bf16x8*>(&As[cur][arow][rch * 8]);
            }
#pragma unroll
            for (int n = 0; n < 2; n++) {
                const int brow = wc * 32 + n * 16 + fr;
                const int rch = (ks * 4 + kg) ^ (brow & 7);
                bfr[n] = *reinterpret_cast<const bf16x8*>(&Bs[cur][brow][rch * 8]);
            }
#pragma unroll
            for (int m = 0; m < 2; m++)
#pragma unroll
                for (int n = 0; n < 2; n++)
                    acc[m][n] = __builtin_amdgcn_mfma_f32_16x16x32_bf16(af[m], bfr[n], acc[m][n], 0, 0, 0);
        }
        __syncthreads();
        cur ^= 1;
    }

#pragma unroll
    for (int n = 0; n < 2; n++) {
        const int col = bn * 64 + wc * 32 + n * 16 + fr;
        const float bv = (MODE == 0 && bias) ? bias[col] : 0.0f;
        const int cp = (MODE == 2) ? ((col >> 11) * SEG + LPAD + (col & 2047)) : col;
#pragma unroll
        for (int m = 0; m < 2; m++) {
            const int row0 = bm * 64 + wr * 32 + m * 16 + kg * 4;
#pragma unroll
            for (int j = 0; j < 4; j++) {
                const int row = row0 + j;
                if (MODE == 0)
                    ((float*)Cout)[(size_t)row * ldc + col] = acc[m][n][j] + bv;
                else
                    ((unsigned short*)Cout)[(size_t)row * ldc + cp] = f2bf(acc[m][n][j]);
            }
        }
    }
}

// ---------------- MFMA banded attention, 32x32x16, d-split --------------------
// wave -> (b, h, 32-row i-tile, 32-d half). 4096 waves, grid 1024 XCD-swizzled.
__global__ __launch_bounds__(256) void attn_mfma(const unsigned short* __restrict__ Vt,
                                                 const float* __restrict__ l2rbuf,
                                                 unsigned short* __restrict__ O) {
    const int wid = threadIdx.x >> 6;
    const int lane = threadIdx.x & 63;
    const int il = lane & 31, hi = lane >> 5;
    const int sbid = (blockIdx.x & 7) * 128 + (blockIdx.x >> 3);
    const int gi = sbid * 4 + wid;             // over (b,h,iblk,dhalf), 4096
    const int dhalf = gi & 1;
    const int iblk = (gi >> 1) & 63;           // N/32 = 64
    const int bh = gi >> 7;
    const int h = bh & 7;
    const int b = bh >> 3;
    const int i0 = iblk * 32;

    const int i = i0 + il;                     // this lane's query row (C col)
    const float l2rf = l2rbuf[((size_t)(b * N + i)) * H + h];

    const unsigned short* Va = Vt + (size_t)(h * DH + dhalf * 32 + il) * LDV
                              + (size_t)b * SEG + (LPAD - AWIN) + i0 + hi * 8;

    f32x16 acc = (f32x16)0.0f;
    __builtin_amdgcn_s_setprio(1);
#pragma unroll
    for (int ks = 0; ks < 8; ks++) {
        const float jb = (float)(ks * 16 + hi * 8 - AWIN - il);
        float wv[8];
#pragma unroll
        for (int e = 0; e < 8; e++)
            wv[e] = __builtin_amdgcn_exp2f(l2rf * __builtin_fabsf(jb + (float)e));
        uint4 uw;
        uw.x = pack2(wv[0], wv[1]); uw.y = pack2(wv[2], wv[3]);
        uw.z = pack2(wv[4], wv[5]); uw.w = pack2(wv[6], wv[7]);
        const bf16x8 pB = __builtin_bit_cast(bf16x8, uw);
        const bf16x8 a0 = *reinterpret_cast<const bf16x8*>(Va + (size_t)ks * 16);
        acc = __builtin_amdgcn_mfma_f32_32x32x16_bf16(a0, pB, acc, 0, 0, 0);
    }
    __builtin_amdgcn_s_setprio(0);

    const float rr = __builtin_amdgcn_exp2f(l2rf);
    const float inv1mr = 1.0f / (1.0f - rr);
    const float rl = __builtin_amdgcn_exp2f(l2rf * (float)(i + 1));
    const float rg = __builtin_amdgcn_exp2f(l2rf * (float)(N - i));
    const float invz = 1.0f / (1.0f + (2.0f * rr - rl - rg) * inv1mr);

    unsigned short* orow = O + ((size_t)(b * N + i)) * D + h * DH + dhalf * 32 + 4 * hi;
#pragma unroll
    for (int q = 0; q < 4; q++) {
        uint2 o0;
        o0.x = pack2(acc[4 * q + 0] * invz, acc[4 * q + 1] * invz);
        o0.y = pack2(acc[4 * q + 2] * invz, acc[4 * q + 3] * invz);
        *reinterpret_cast<uint2*>(orow + 8 * q) = o0;
    }
}

extern "C" void kernel_launch(void* const* d_in, const int* in_sizes, int n_in,
                              void* d_out, int out_size, void* d_ws, size_t ws_size,
                              hipStream_t stream) {
    const float* x      = (const float*)d_in[0];   // (B,N,D)
    const float* W_v    = (const float*)d_in[1];   // (D, 512)
    const float* W_sig  = (const float*)d_in[2];   // (D, H)
    const float* b_sig  = (const float*)d_in[3];   // (H,)
    const float* W_out  = (const float*)d_in[4];   // (512, D)
    const float* b_out  = (const float*)d_in[5];   // (D,)
    float* out = (float*)d_out;

    char* ws = (char*)d_ws;
    unsigned short* Vt   = (unsigned short*)ws;                                // 8.75 MB
    unsigned short* xbf  = (unsigned short*)(ws + (size_t)9  * 1024 * 1024);   // 8 MB (reused as attnOut)
    unsigned short* WvT  = (unsigned short*)(ws + (size_t)17 * 1024 * 1024);   // 512 KB
    unsigned short* WoT  = (unsigned short*)(ws + (size_t)17 * 1024 * 1024 + 524288);
    float*          l2r  = (float*)(ws + (size_t)18 * 1024 * 1024);            // 256 KB
    unsigned short* attnOut = xbf;   // xbf dead after GEMM1

    prep_fused<<<2240, 256, 0, stream>>>(x, W_sig, b_sig, W_v, W_out,
                                         xbf, l2r, WvT, WoT, Vt);

    // 1) Vt = (x @ W_v)^T, bf16, column-padded per batch
    {
        dim3 grid(128, 8);
        gemm_bf16<2><<<grid, 256, 0, stream>>>(WvT, xbf, nullptr, Vt, LDV);
    }
    // 2) banded MFMA attention (32x32, d-split) -> bf16 row-major O
    attn_mfma<<<1024, 256, 0, stream>>>(Vt, l2r, attnOut);
    // 3) out = attnOut @ W_out + b_out (f32), 1D grid 1024, XCD-swizzled
    gemm_bf16<0><<<1024, 256, 0, stream>>>(attnOut, WoT, b_out, out, D);
}

// Round 18
// 56.950 us; speedup vs baseline: 4.5911x; 1.0049x over previous
//
#include <hip/hip_runtime.h>
#include <hip/hip_bf16.h>

// Problem constants
#define B 4
#define N 2048
#define D 512
#define H 8
#define DH 64
#define ROWS (B * N)        // 8192
#define AWIN 40             // attn band half-width; tail < 1.4e-4 relative
#define NKS ((2 * AWIN + 32) / 16)   // 7 MFMA k-steps
#define LPAD 64             // left col pad in Vt
#define RPAD 128            // right col pad in Vt
#define SEG (LPAD + N + RPAD)   // 2240 cols per batch in Vt
#define LDV (B * SEG)           // 8960 = Vt row length

using bf16x8 = __attribute__((ext_vector_type(8))) short;
using f32x4  = __attribute__((ext_vector_type(4))) float;
using f32x16 = __attribute__((ext_vector_type(16))) float;

static __device__ __forceinline__ unsigned short f2bf(float f) {
    unsigned u = __builtin_bit_cast(unsigned, f);
    u += 0x7fffu + ((u >> 16) & 1u);        // round-to-nearest-even
    return (unsigned short)(u >> 16);
}
static __device__ __forceinline__ unsigned pack2(float a, float b) {
    return (unsigned)f2bf(a) | ((unsigned)f2bf(b) << 16);
}

// ------------- fused prep: x->bf16 + f32 sigma (blocks 0..2047),
//               WvT (2048..2111), WoT (2112..2175), Vt pad zero (2176..2239) ---
__global__ __launch_bounds__(256) void prep_fused(const float* __restrict__ x,
                                                  const float* __restrict__ Ws,
                                                  const float* __restrict__ bs,
                                                  const float* __restrict__ Wv,
                                                  const float* __restrict__ Wo,
                                                  unsigned short* __restrict__ xbf,
                                                  float* __restrict__ l2rbuf,
                                                  unsigned short* __restrict__ WvT,
                                                  unsigned short* __restrict__ WoT,
                                                  unsigned short* __restrict__ Vt) {
    __shared__ float tile[64][65];
    const int bx = blockIdx.x;

    if (bx < 2048) {
        // ---- x convert + f32 sigma (precision-critical: feeds exp chain) ----
        const int wid = threadIdx.x >> 6, lane = threadIdx.x & 63;
        const int row = bx * 4 + wid;
        const float* xr = x + (size_t)row * D + lane * 8;
        const float4 a = *reinterpret_cast<const float4*>(xr);
        const float4 c = *reinterpret_cast<const float4*>(xr + 4);
        float v[8] = {a.x, a.y, a.z, a.w, c.x, c.y, c.z, c.w};

        uint4 o;
        o.x = pack2(v[0], v[1]); o.y = pack2(v[2], v[3]);
        o.z = pack2(v[4], v[5]); o.w = pack2(v[6], v[7]);
        *reinterpret_cast<uint4*>(xbf + (size_t)row * D + lane * 8) = o;

        const float4* Ws4 = reinterpret_cast<const float4*>(Ws);   // (D, 8)
        f32x4 alo = (f32x4)0.0f, ahi = (f32x4)0.0f;
#pragma unroll
        for (int j = 0; j < 8; j++) {
            const int e = lane * 8 + j;
            const float4 wl = Ws4[e * 2], wh = Ws4[e * 2 + 1];
            alo[0] += v[j] * wl.x; alo[1] += v[j] * wl.y; alo[2] += v[j] * wl.z; alo[3] += v[j] * wl.w;
            ahi[0] += v[j] * wh.x; ahi[1] += v[j] * wh.y; ahi[2] += v[j] * wh.z; ahi[3] += v[j] * wh.w;
        }
#pragma unroll
        for (int off = 1; off < 64; off <<= 1) {
#pragma unroll
            for (int c2 = 0; c2 < 4; c2++) {
                alo[c2] += __shfl_xor(alo[c2], off, 64);
                ahi[c2] += __shfl_xor(ahi[c2], off, 64);
            }
        }
        if (lane < 8) {
            const int h = lane;
            const float acc = (h < 4) ? alo[h] : ahi[h - 4];
            const float z = acc + bs[h];
            const float sig = 1.0f / (1.0f + expf(-z));
            const float s = expf(sig) + 1.0f;
            l2rbuf[(size_t)row * H + h] = -1.4426950408889634f / s;
        }
        return;
    }

    if (bx < 2176) {
        // ---- W transpose+convert ----
        const int idx = bx - 2048;
        const bool second = idx >= 64;
        const int id2 = idx & 63;
        const float* src = second ? Wo : Wv;
        unsigned short* dst = second ? WoT : WvT;
        const int n0 = (id2 & 7) * 64, k0 = (id2 >> 3) * 64;
        const int tr = threadIdx.x >> 4, tc = threadIdx.x & 15;
#pragma unroll
        for (int it = 0; it < 4; it++) {
            const int r = it * 16 + tr;
            const float4 v = *reinterpret_cast<const float4*>(&src[(size_t)(k0 + r) * 512 + n0 + tc * 4]);
            tile[r][tc * 4 + 0] = v.x; tile[r][tc * 4 + 1] = v.y;
            tile[r][tc * 4 + 2] = v.z; tile[r][tc * 4 + 3] = v.w;
        }
        __syncthreads();
#pragma unroll
        for (int it = 0; it < 4; it++) {
            const int r = it * 16 + tr;
            ushort4 o;
            o.x = f2bf(tile[tc * 4 + 0][r]); o.y = f2bf(tile[tc * 4 + 1][r]);
            o.z = f2bf(tile[tc * 4 + 2][r]); o.w = f2bf(tile[tc * 4 + 3][r]);
            *reinterpret_cast<ushort4*>(&dst[(size_t)(n0 + r) * 512 + k0 + tc * 4]) = o;
        }
        return;
    }

    // ---- zero pad cols of Vt ----
    {
        const int idx = bx - 2176;   // 0..63
        for (int t = idx * 256 + threadIdx.x; t < 512 * 4 * 24; t += 64 * 256) {
            const int c = t % 24;
            const int bb = (t / 24) & 3;
            const int row = t / 96;
            const int col = (c < 8) ? bb * SEG + c * 8 : bb * SEG + LPAD + N + (c - 8) * 8;
            *reinterpret_cast<uint4*>(Vt + (size_t)row * LDV + col) = uint4{0, 0, 0, 0};
        }
    }
}

// ---------------- bf16 MFMA GEMM, 64x64 tile, GBK=64, double-buffered ---------
// LDS XOR-swizzle (rule #21): linear LDS dest, pre-swizzled GLOBAL source chunk
// (ch ^ (row&7)), and the same XOR applied on the ds_read col.
// MODE 0: f32 out + bias, 1D grid 1024 with bijective XCD swizzle.
// MODE 2: bf16 out into Vt with col remap, 2D grid (bn=128, bm=8).
#define GBK 64
#define GK  512

template <int MODE>
__global__ __launch_bounds__(256) void gemm_bf16(const unsigned short* __restrict__ A,
                                                 const unsigned short* __restrict__ Bt,
                                                 const float* __restrict__ bias,
                                                 void* __restrict__ Cout,
                                                 int ldc) {
    __shared__ unsigned short As[2][64][GBK];   // 8 KB x2
    __shared__ unsigned short Bs[2][64][GBK];   // 8 KB x2 (32 KB total)
    const int tid = threadIdx.x;
    const int lane = tid & 63, wid = tid >> 6;
    const int wr = wid >> 1, wc = wid & 1;      // 2x2 waves: 32x32 each
    int bm, bn;
    if (MODE == 0) {
        const int xcd = blockIdx.x & 7, idx = blockIdx.x >> 3;
        bm = xcd * 16 + (idx >> 3);
        bn = idx & 7;
    } else {
        bn = blockIdx.x; bm = blockIdx.y;
    }
    const int fr = lane & 15, kg = lane >> 4;

    f32x4 acc[2][2] = {};

    const unsigned short* Ab = A + (size_t)bm * 64 * GK;
    const unsigned short* Bb = Bt + (size_t)bn * 64 * GK;
    const int r32 = tid >> 3, ch = tid & 7;     // 32 rows/pass, chunk 0..7

    auto stage = [&](int buf, int k0) {
#pragma unroll
        for (int it = 0; it < 2; it++) {
            const int row = it * 32 + r32;
            const int gch = ch ^ (row & 7);     // pre-swizzled global source
            const unsigned short* g = Ab + (size_t)row * GK + k0 + gch * 8;
            __builtin_amdgcn_global_load_lds(
                (const __attribute__((address_space(1))) void*)g,
                (__attribute__((address_space(3))) void*)&As[buf][row][ch * 8], 16, 0, 0);
        }
#pragma unroll
        for (int it = 0; it < 2; it++) {
            const int row = it * 32 + r32;
            const int gch = ch ^ (row & 7);
            const unsigned short* g = Bb + (size_t)row * GK + k0 + gch * 8;
            __builtin_amdgcn_global_load_lds(
                (const __attribute__((address_space(1))) void*)g,
                (__attribute__((address_space(3))) void*)&Bs[buf][row][ch * 8], 16, 0, 0);
        }
    };

    stage(0, 0);
    __syncthreads();
    int cur = 0;
#pragma unroll
    for (int kt = 0; kt < GK / GBK; kt++) {
        if (kt + 1 < GK / GBK) stage(cur ^ 1, (kt + 1) * GBK);
#pragma unroll
        for (int ks = 0; ks < 2; ks++) {
            bf16x8 af[2], bfr[2];
#pragma unroll
            for (int m = 0; m < 2; m++) {
                const int arow = wr * 32 + m * 16 + fr;
                const int rch = (ks * 4 + kg) ^ (arow & 7);   // swizzled read col
                af[m] = *reinterpret_cast<const bf16x8*>(&As[cur][arow][rch * 8]);
            }
#pragma unroll
            for (int n = 0; n < 2; n++) {
                const int brow = wc * 32 + n * 16 + fr;
                const int rch = (ks * 4 + kg) ^ (brow & 7);
                bfr[n] = *reinterpret_cast<const bf16x8*>(&Bs[cur][brow][rch * 8]);
            }
#pragma unroll
            for (int m = 0; m < 2; m++)
#pragma unroll
                for (int n = 0; n < 2; n++)
                    acc[m][n] = __builtin_amdgcn_mfma_f32_16x16x32_bf16(af[m], bfr[n], acc[m][n], 0, 0, 0);
        }
        __syncthreads();
        cur ^= 1;
    }

#pragma unroll
    for (int n = 0; n < 2; n++) {
        const int col = bn * 64 + wc * 32 + n * 16 + fr;
        const float bv = (MODE == 0 && bias) ? bias[col] : 0.0f;
        const int cp = (MODE == 2) ? ((col >> 11) * SEG + LPAD + (col & 2047)) : col;
#pragma unroll
        for (int m = 0; m < 2; m++) {
            const int row0 = bm * 64 + wr * 32 + m * 16 + kg * 4;
#pragma unroll
            for (int j = 0; j < 4; j++) {
                const int row = row0 + j;
                if (MODE == 0)
                    ((float*)Cout)[(size_t)row * ldc + col] = acc[m][n][j] + bv;
                else
                    ((unsigned short*)Cout)[(size_t)row * ldc + cp] = f2bf(acc[m][n][j]);
            }
        }
    }
}

// ---------------- MFMA banded attention, 32x32x16, d-split, band ±40 ----------
// wave -> (b, h, 32-row i-tile, 32-d half). 4096 waves, grid 1024 XCD-swizzled.
__global__ __launch_bounds__(256) void attn_mfma(const unsigned short* __restrict__ Vt,
                                                 const float* __restrict__ l2rbuf,
                                                 unsigned short* __restrict__ O) {
    const int wid = threadIdx.x >> 6;
    const int lane = threadIdx.x & 63;
    const int il = lane & 31, hi = lane >> 5;
    const int sbid = (blockIdx.x & 7) * 128 + (blockIdx.x >> 3);
    const int gi = sbid * 4 + wid;             // over (b,h,iblk,dhalf), 4096
    const int dhalf = gi & 1;
    const int iblk = (gi >> 1) & 63;           // N/32 = 64
    const int bh = gi >> 7;
    const int h = bh & 7;
    const int b = bh >> 3;
    const int i0 = iblk * 32;

    const int i = i0 + il;                     // this lane's query row (C col)
    const float l2rf = l2rbuf[((size_t)(b * N + i)) * H + h];

    const unsigned short* Va = Vt + (size_t)(h * DH + dhalf * 32 + il) * LDV
                              + (size_t)b * SEG + (LPAD - AWIN) + i0 + hi * 8;

    f32x16 acc = (f32x16)0.0f;
    __builtin_amdgcn_s_setprio(1);
#pragma unroll
    for (int ks = 0; ks < NKS; ks++) {
        const float jb = (float)(ks * 16 + hi * 8 - AWIN - il);
        float wv[8];
#pragma unroll
        for (int e = 0; e < 8; e++)
            wv[e] = __builtin_amdgcn_exp2f(l2rf * __builtin_fabsf(jb + (float)e));
        uint4 uw;
        uw.x = pack2(wv[0], wv[1]); uw.y = pack2(wv[2], wv[3]);
        uw.z = pack2(wv[4], wv[5]); uw.w = pack2(wv[6], wv[7]);
        const bf16x8 pB = __builtin_bit_cast(bf16x8, uw);
        const bf16x8 a0 = *reinterpret_cast<const bf16x8*>(Va + (size_t)ks * 16);
        acc = __builtin_amdgcn_mfma_f32_32x32x16_bf16(a0, pB, acc, 0, 0, 0);
    }
    __builtin_amdgcn_s_setprio(0);

    const float rr = __builtin_amdgcn_exp2f(l2rf);
    const float inv1mr = 1.0f / (1.0f - rr);
    const float rl = __builtin_amdgcn_exp2f(l2rf * (float)(i + 1));
    const float rg = __builtin_amdgcn_exp2f(l2rf * (float)(N - i));
    const float invz = 1.0f / (1.0f + (2.0f * rr - rl - rg) * inv1mr);

    unsigned short* orow = O + ((size_t)(b * N + i)) * D + h * DH + dhalf * 32 + 4 * hi;
#pragma unroll
    for (int q = 0; q < 4; q++) {
        uint2 o0;
        o0.x = pack2(acc[4 * q + 0] * invz, acc[4 * q + 1] * invz);
        o0.y = pack2(acc[4 * q + 2] * invz, acc[4 * q + 3] * invz);
        *reinterpret_cast<uint2*>(orow + 8 * q) = o0;
    }
}

extern "C" void kernel_launch(void* const* d_in, const int* in_sizes, int n_in,
                              void* d_out, int out_size, void* d_ws, size_t ws_size,
                              hipStream_t stream) {
    const float* x      = (const float*)d_in[0];   // (B,N,D)
    const float* W_v    = (const float*)d_in[1];   // (D, 512)
    const float* W_sig  = (const float*)d_in[2];   // (D, H)
    const float* b_sig  = (const float*)d_in[3];   // (H,)
    const float* W_out  = (const float*)d_in[4];   // (512, D)
    const float* b_out  = (const float*)d_in[5];   // (D,)
    float* out = (float*)d_out;

    char* ws = (char*)d_ws;
    unsigned short* Vt   = (unsigned short*)ws;                                // 8.75 MB
    unsigned short* xbf  = (unsigned short*)(ws + (size_t)9  * 1024 * 1024);   // 8 MB (reused as attnOut)
    unsigned short* WvT  = (unsigned short*)(ws + (size_t)17 * 1024 * 1024);   // 512 KB
    unsigned short* WoT  = (unsigned short*)(ws + (size_t)17 * 1024 * 1024 + 524288);
    float*          l2r  = (float*)(ws + (size_t)18 * 1024 * 1024);            // 256 KB
    unsigned short* attnOut = xbf;   // xbf dead after GEMM1

    prep_fused<<<2240, 256, 0, stream>>>(x, W_sig, b_sig, W_v, W_out,
                                         xbf, l2r, WvT, WoT, Vt);

    // 1) Vt = (x @ W_v)^T, bf16, column-padded per batch
    {
        dim3 grid(128, 8);
        gemm_bf16<2><<<grid, 256, 0, stream>>>(WvT, xbf, nullptr, Vt, LDV);
    }
    // 2) banded MFMA attention (32x32, d-split, ±40 band) -> bf16 row-major O
    attn_mfma<<<1024, 256, 0, stream>>>(Vt, l2r, attnOut);
    // 3) out = attnOut @ W_out + b_out (f32), 1D grid 1024, XCD-swizzled
    gemm_bf16<0><<<1024, 256, 0, stream>>>(attnOut, WoT, b_out, out, D);
}